// Round 1
// 184970.874 us; speedup vs baseline: 1.4501x; 1.4501x over previous
//
#include <hip/hip_runtime.h>
#include <math.h>

#define TT 512
#define BB 64
#define HH 1024
#define KK 2048          // IN + H
#define NWGL 128         // WGs per layer
#define ROWS 8           // H rows per WG
#define RING_D 8         // h0 ring depth
#define BH (BB*HH)       // 65536 floats per timestep

// LDS layout (floats):
//   Wl    [ROWS][KK]        = 16384   (64 KB, resident weights)
//   buf   [4 waves][64][65] = 16640   (stride-65 transpose staging, conflict-free)
//   parts [4][64][ROWS]     = 2048    (cross-wave partial sums)
#define LDS_FLOATS (16384 + 16640 + 2048)

typedef float floatx4 __attribute__((ext_vector_type(4)));

// ---------------------------------------------------------------------------
// Coherence protocol (R2): NO cache-wide maintenance ops in the steady loop.
//
// The previous version called __threadfence() per step per WG. On gfx950 that
// is a full acq_rel agent fence -> buffer_wbl2 + buffer_inv (cache-wide L2
// writeback + invalidate walks). rocprof: 469 GB TCC traffic/dispatch
// (916 MB/step; writes amplified ~1000x by dirty-L2 writeback walks), and the
// invalidates destroyed cross-WG L2 sharing of x[t]. VALUBusy 2%.
//
// New protocol:
//   * cross-WG-visible data (h ring / out) moves ONLY through agent-scope
//     sc1 (L2-bypassing) loads/stores -> coherent at the L3/fabric point,
//     no cache maintenance needed, ever.
//   * x[t] and the LDS-resident weights use normal cached loads (read-only
//     input; kernel-dispatch acquire makes them fresh; L2 sharing restored).
//   * publish  = __syncthreads() (drains vmcnt(0) per wave, i.e. all sc1
//     stores acked at the coherence point) + RELAXED agent fetch_add.
//   * consume  = RELAXED agent spin + __syncthreads() (compiler+HW ordering)
//     + sc1 data loads. No buffer_inv needed: the data reads bypass L2.
// ---------------------------------------------------------------------------

__device__ __forceinline__ void spin_ge(int* p, int target) {
    int it = 0;
    while (__hip_atomic_load(p, __ATOMIC_RELAXED, __HIP_MEMORY_SCOPE_AGENT) < target) {
        __builtin_amdgcn_s_sleep(4);
        if (++it > (1 << 21)) return;  // failsafe: fail loud (absmax), never hang
    }
}

// Agent-scope (sc1) scalar store: visible at the coherence point, no L2 dirty line.
__device__ __forceinline__ void st_agent(float* p, float v) {
    __hip_atomic_store(p, v, __ATOMIC_RELAXED, __HIP_MEMORY_SCOPE_AGENT);
}

// Stage one 1024-wide half of the input (this wave's 256-k quarter, 4 chunks of 64)
// into LDS transposed [k][b], then accumulate 8 rows.
// BYPASS=true: 16-deep burst of global_load_dwordx4 sc1 (L2-bypass, coherent at L3),
// single vmcnt(0), sched_barrier(0) so no consumer is scheduled before the wait.
template<bool BYPASS>
__device__ __forceinline__ void stage_and_accum(
    const float* __restrict__ src,   // [BB][1024], row-major
    const float* __restrict__ Wl,    // LDS [ROWS][KK]
    float* __restrict__ bufW,        // this wave's [64][65] region
    int kq,                          // wave quarter offset: 256*wave
    int wof,                         // W k-offset for this half: 0 or 1024
    int lane,
    float acc[ROWS])
{
    const int bsub = lane >> 4;          // 0..3
    const int kk4  = (lane & 15) * 4;    // 0..60
    #pragma unroll
    for (int c = 0; c < 4; ++c) {
        const int k0 = kq + c * 64;
        if (BYPASS) {
            floatx4 v[16];
            #pragma unroll
            for (int i = 0; i < 16; ++i) {
                const float* p = src + (i * 4 + bsub) * 1024 + k0 + kk4;
                asm volatile("global_load_dwordx4 %0, %1, off sc1"
                             : "=v"(v[i]) : "v"(p));
            }
            asm volatile("s_waitcnt vmcnt(0)" ::: "memory");
            __builtin_amdgcn_sched_barrier(0);   // pin: no consumer before the wait
            #pragma unroll
            for (int i = 0; i < 16; ++i) {
                const int b = i * 4 + bsub;
                bufW[(kk4 + 0) * 65 + b] = v[i][0];
                bufW[(kk4 + 1) * 65 + b] = v[i][1];
                bufW[(kk4 + 2) * 65 + b] = v[i][2];
                bufW[(kk4 + 3) * 65 + b] = v[i][3];
            }
        } else {
            #pragma unroll
            for (int i = 0; i < 16; ++i) {
                const int b = i * 4 + bsub;
                const float4 v = *(const float4*)(src + b * 1024 + k0 + kk4);
                bufW[(kk4 + 0) * 65 + b] = v.x;
                bufW[(kk4 + 1) * 65 + b] = v.y;
                bufW[(kk4 + 2) * 65 + b] = v.z;
                bufW[(kk4 + 3) * 65 + b] = v.w;
            }
        }
        // Per-wave LDS ops are processed in order: no barrier needed (per-wave buffer).
        const float* bk = bufW + lane;
        #pragma unroll
        for (int kk = 0; kk < 64; kk += 4) {
            const float i0 = bk[(kk + 0) * 65];
            const float i1 = bk[(kk + 1) * 65];
            const float i2 = bk[(kk + 2) * 65];
            const float i3 = bk[(kk + 3) * 65];
            #pragma unroll
            for (int r = 0; r < ROWS; ++r) {
                const float4 w = *(const float4*)(Wl + r * KK + wof + k0 + kk);
                acc[r] += w.x * i0 + w.y * i1 + w.z * i2 + w.w * i3;
            }
        }
    }
}

extern "C" __global__ void rnn_init(int* __restrict__ c) {
    const int i = blockIdx.x * blockDim.x + threadIdx.x;
    if (i < 1024) c[i] = 0;
}

extern "C" __global__ void __launch_bounds__(256, 1)
rnn_persist(const float* __restrict__ x,      // [T][B][IN]
            const float* __restrict__ h0init, // [2][B][H]
            const float* __restrict__ Wih0, const float* __restrict__ bih0,
            const float* __restrict__ Whh0, const float* __restrict__ bhh0,
            const float* __restrict__ Wih1, const float* __restrict__ bih1,
            const float* __restrict__ Whh1, const float* __restrict__ bhh1,
            float* __restrict__ out,          // [T][B][H] then [2][B][H]
            int* __restrict__ c0, int* __restrict__ c1,
            float* __restrict__ ring)         // [RING_D][B][H]
{
    extern __shared__ float lds[];
    float* Wl    = lds;                      // 16384 floats
    float* buf   = lds + ROWS * KK;          // 4*64*65
    float* parts = buf + 4 * 64 * 65;        // 4*64*8

    const int wg   = blockIdx.x;
    const bool isL1 = (wg >= NWGL);
    const int g    = isL1 ? wg - NWGL : wg;
    const int rbase = g * ROWS;
    const int tid  = threadIdx.x;
    const int wv   = tid >> 6;
    const int lane = tid & 63;
    const int kq   = wv * 256;
    float* bufW = buf + wv * (64 * 65);

    // Load this WG's weight rows into LDS once (resident for all 512 steps).
    const float* Wa = isL1 ? Wih1 : Wih0;    // k-half 0 (input half)
    const float* Wb = isL1 ? Whh1 : Whh0;    // k-half 1 (recurrent half)
    for (int idx = tid; idx < ROWS * 256; idx += 256) {
        const int r  = idx >> 8;
        const int k4 = (idx & 255) * 4;
        *(float4*)(Wl + r * KK + k4)        = *(const float4*)(Wa + (size_t)(rbase + r) * HH + k4);
        *(float4*)(Wl + r * KK + 1024 + k4) = *(const float4*)(Wb + (size_t)(rbase + r) * HH + k4);
    }
    const int er = tid & 7;  // output row (same for tid and tid+256)
    const float bsum = isL1 ? (bih1[rbase + er] + bhh1[rbase + er])
                            : (bih0[rbase + er] + bhh0[rbase + er]);
    __syncthreads();

    for (int t = 0; t < TT; ++t) {
        float acc[ROWS];
        #pragma unroll
        for (int r = 0; r < ROWS; ++r) acc[r] = 0.f;

        if (!isL1) {
            // Phase A: x[t] half — no dependency, hides the wait below.
            // Normal cached loads: x is read-only, 16 L0 WGs/XCD share it in L2.
            stage_and_accum<false>(x + (size_t)t * BH, Wl, bufW, kq, 0, lane, acc);
            if (tid == 0) {
                if (t >= 1)      spin_ge(c0 + (t - 1), NWGL);      // h0[t-1] ready
                if (t >= RING_D) spin_ge(c1 + (t - RING_D), NWGL); // ring slot reusable
            }
            __syncthreads();   // publishes spin result to all waves; compiler+HW order
            // Phase B: h0[t-1] half (recurrent, W_hh0 => wof 1024), sc1 bypass reads
            const float* hp = (t == 0) ? h0init
                                       : ring + (size_t)((t - 1) % RING_D) * BH;
            stage_and_accum<true>(hp, Wl, bufW, kq, 1024, lane, acc);
        } else {
            if (tid == 0 && t >= 1) {
                spin_ge(c1 + (t - 1), NWGL);   // h1[t-1] ready
            }
            __syncthreads();
            // Phase A: h1[t-1] half (recurrent, W_hh1 => wof 1024)
            const float* hp = (t == 0) ? (h0init + BH)
                                       : (out + (size_t)(t - 1) * BH);
            stage_and_accum<true>(hp, Wl, bufW, kq, 1024, lane, acc);
            if (tid == 0) {
                spin_ge(c0 + t, NWGL);         // h0[t] ready
            }
            __syncthreads();
            // Phase B: h0[t] half (input half, W_ih1 => wof 0)
            stage_and_accum<true>(ring + (size_t)(t % RING_D) * BH, Wl, bufW, kq, 0, lane, acc);
        }

        // Cross-wave reduction: partials [w][b][r]
        float* pw = parts + (size_t)(wv * 64 + lane) * ROWS;
        *(float4*)(pw + 0) = make_float4(acc[0], acc[1], acc[2], acc[3]);
        *(float4*)(pw + 4) = make_float4(acc[4], acc[5], acc[6], acc[7]);
        __syncthreads();

        for (int o = tid; o < 512; o += 256) {
            const int b = o >> 3;
            const int r = o & 7;
            const float s = parts[o] + parts[o + 512] + parts[o + 1024] + parts[o + 1536] + bsum;
            const float hv = tanhf(s);
            const int col = rbase + r;
            if (!isL1) {
                st_agent(ring + (size_t)(t % RING_D) * BH + b * HH + col, hv);
                if (t == TT - 1) st_agent(out + (size_t)TT * BH + b * HH + col, hv);      // h0_n
            } else {
                st_agent(out + (size_t)t * BH + b * HH + col, hv);                        // outputs
                if (t == TT - 1) st_agent(out + (size_t)TT * BH + BH + b * HH + col, hv); // h1_n
            }
        }
        // __syncthreads emits s_waitcnt vmcnt(0) per wave before s_barrier =>
        // after the barrier ALL waves' sc1 stores are acked at the coherence
        // point. The relaxed agent fetch_add below is therefore a valid release
        // for this protocol (no dirty L2 lines to flush: all shared stores are sc1).
        __syncthreads();
        if (tid == 0) {
            asm volatile("s_waitcnt vmcnt(0)" ::: "memory");  // belt-and-braces
            __hip_atomic_fetch_add(isL1 ? (c1 + t) : (c0 + t), 1,
                                   __ATOMIC_RELAXED, __HIP_MEMORY_SCOPE_AGENT);
        }
    }
}

extern "C" void kernel_launch(void* const* d_in, const int* in_sizes, int n_in,
                              void* d_out, int out_size, void* d_ws, size_t ws_size,
                              hipStream_t stream) {
    const float* x    = (const float*)d_in[0];
    const float* h0i  = (const float*)d_in[1];
    const float* Wih0 = (const float*)d_in[2];
    const float* bih0 = (const float*)d_in[3];
    const float* Whh0 = (const float*)d_in[4];
    const float* bhh0 = (const float*)d_in[5];
    const float* Wih1 = (const float*)d_in[6];
    const float* bih1 = (const float*)d_in[7];
    const float* Whh1 = (const float*)d_in[8];
    const float* bhh1 = (const float*)d_in[9];
    float* out = (float*)d_out;

    int*   c0   = (int*)d_ws;             // [512]
    int*   c1   = c0 + 512;               // [512]
    float* ring = (float*)((char*)d_ws + 8192);  // [RING_D][B][H]

    (void)hipFuncSetAttribute((const void*)rnn_persist,
                              hipFuncAttributeMaxDynamicSharedMemorySize,
                              LDS_FLOATS * 4);

    rnn_init<<<4, 256, 0, stream>>>(c0);
    rnn_persist<<<256, 256, LDS_FLOATS * 4, stream>>>(
        x, h0i, Wih0, bih0, Whh0, bhh0, Wih1, bih1, Whh1, bhh1,
        out, c0, c1, ring);
}

// Round 3
// 22642.203 us; speedup vs baseline: 11.8462x; 8.1693x over previous
//
#include <hip/hip_runtime.h>
#include <math.h>

#define TT 512
#define BB 64
#define HH 1024
#define KK 2048          // IN + H
#define NWGL 128         // WGs per layer
#define ROWS 8           // H rows per WG
#define RING_D 8         // h0 ring depth
#define BH (BB*HH)       // 65536 floats per timestep

// LDS layout (floats):
//   Wl    [ROWS][KK]        = 16384   (64 KB, resident weights)
//   buf   [4 waves][64][65] = 16640   (stride-65 transpose staging, conflict-free)
//   parts [4][64][ROWS]     = 2048    (cross-wave partial sums)
#define LDS_FLOATS (16384 + 16640 + 2048)

typedef float floatx4 __attribute__((ext_vector_type(4)));

// ---------------------------------------------------------------------------
// R3: revert R2's cross-XCD cached-h protocol (stale-partial-line hazard:
// producer sc1 write-throughs can leave mixed fresh/stale lines in the
// producer's own XCD L2, which same-XCD consumers' cached reads then hit).
// Back to the R1-verified protocol: h moves ONLY via sc1 loads/stores.
//
// The one new variable vs R1: REGISTER PRESSURE. R0/R1 both show
// VGPR_Count==256 (the encoding cap) and ~500 MB/step of WRITE traffic that
// no data flow explains -> scratch spill writeback. Root cause: the staging
// c-loop is fully unrolled by the compiler, hoisting up to 64 float4 loads
// (=256 VGPRs) in flight. Fix: #pragma unroll 1 on the c-loop (both paths)
// + bypass bursts of 8. Peak live regs by construction ~130.
// ---------------------------------------------------------------------------

__device__ __forceinline__ void spin_ge(int* p, int target) {
    int it = 0;
    while (__hip_atomic_load(p, __ATOMIC_RELAXED, __HIP_MEMORY_SCOPE_AGENT) < target) {
        __builtin_amdgcn_s_sleep(4);
        if (++it > (1 << 21)) return;  // failsafe: fail loud (absmax), never hang
    }
}

// Agent-scope (sc1) scalar store: write-through to the coherence point.
__device__ __forceinline__ void st_agent(float* p, float v) {
    __hip_atomic_store(p, v, __ATOMIC_RELAXED, __HIP_MEMORY_SCOPE_AGENT);
}

// Stage one 1024-wide half of the input (this wave's 256-k quarter, 4 chunks of 64)
// into LDS transposed [k][b], then accumulate 8 rows.
// BYPASS=true : sc1 (L2-bypass, coherent at fabric) reads in bursts of 8.
// BYPASS=false: normal cached loads, 16 in flight within one chunk only.
template<bool BYPASS>
__device__ __forceinline__ void stage_and_accum(
    const float* __restrict__ src,   // [BB][1024], row-major
    const float* __restrict__ Wl,    // LDS [ROWS][KK]
    float* __restrict__ bufW,        // this wave's [64][65] region
    int kq,                          // wave quarter offset: 256*wave
    int wof,                         // W k-offset for this half: 0 or 1024
    int lane,
    float acc[ROWS])
{
    const int bsub = lane >> 4;          // 0..3
    const int kk4  = (lane & 15) * 4;    // 0..60
    #pragma unroll 1                     // KEY: no cross-chunk load hoisting (VGPR cap!)
    for (int c = 0; c < 4; ++c) {
        const int k0 = kq + c * 64;
        if (BYPASS) {
            #pragma unroll 1             // two bursts of 8: cap live staging regs at 32
            for (int hf = 0; hf < 2; ++hf) {
                floatx4 v[8];
                #pragma unroll
                for (int i = 0; i < 8; ++i) {
                    const float* p = src + ((hf * 8 + i) * 4 + bsub) * 1024 + k0 + kk4;
                    asm volatile("global_load_dwordx4 %0, %1, off sc1"
                                 : "=v"(v[i]) : "v"(p));
                }
                asm volatile("s_waitcnt vmcnt(0)" ::: "memory");
                __builtin_amdgcn_sched_barrier(0);   // pin: no consumer before wait
                #pragma unroll
                for (int i = 0; i < 8; ++i) {
                    const int b = (hf * 8 + i) * 4 + bsub;
                    bufW[(kk4 + 0) * 65 + b] = v[i][0];
                    bufW[(kk4 + 1) * 65 + b] = v[i][1];
                    bufW[(kk4 + 2) * 65 + b] = v[i][2];
                    bufW[(kk4 + 3) * 65 + b] = v[i][3];
                }
            }
        } else {
            #pragma unroll
            for (int i = 0; i < 16; ++i) {
                const int b = i * 4 + bsub;
                const float4 v = *(const float4*)(src + b * 1024 + k0 + kk4);
                bufW[(kk4 + 0) * 65 + b] = v.x;
                bufW[(kk4 + 1) * 65 + b] = v.y;
                bufW[(kk4 + 2) * 65 + b] = v.z;
                bufW[(kk4 + 3) * 65 + b] = v.w;
            }
        }
        // Per-wave LDS ops are processed in order: no barrier needed (per-wave buffer).
        const float* bk = bufW + lane;
        #pragma unroll
        for (int kk = 0; kk < 64; kk += 4) {
            const float i0 = bk[(kk + 0) * 65];
            const float i1 = bk[(kk + 1) * 65];
            const float i2 = bk[(kk + 2) * 65];
            const float i3 = bk[(kk + 3) * 65];
            #pragma unroll
            for (int r = 0; r < ROWS; ++r) {
                const float4 w = *(const float4*)(Wl + r * KK + wof + k0 + kk);
                acc[r] += w.x * i0 + w.y * i1 + w.z * i2 + w.w * i3;
            }
        }
    }
}

extern "C" __global__ void rnn_init(int* __restrict__ c) {
    const int i = blockIdx.x * blockDim.x + threadIdx.x;
    if (i < 1024) c[i] = 0;
}

extern "C" __global__ void __launch_bounds__(256, 1)
rnn_persist(const float* __restrict__ x,      // [T][B][IN]
            const float* __restrict__ h0init, // [2][B][H]
            const float* __restrict__ Wih0, const float* __restrict__ bih0,
            const float* __restrict__ Whh0, const float* __restrict__ bhh0,
            const float* __restrict__ Wih1, const float* __restrict__ bih1,
            const float* __restrict__ Whh1, const float* __restrict__ bhh1,
            float* __restrict__ out,          // [T][B][H] then [2][B][H]
            int* __restrict__ c0, int* __restrict__ c1,
            float* __restrict__ ring)         // [RING_D][B][H]
{
    extern __shared__ float lds[];
    float* Wl    = lds;                      // 16384 floats
    float* buf   = lds + ROWS * KK;          // 4*64*65
    float* parts = buf + 4 * 64 * 65;        // 4*64*8

    const int wg   = blockIdx.x;
    const bool isL1 = (wg >= NWGL);
    const int g    = isL1 ? wg - NWGL : wg;
    const int rbase = g * ROWS;
    const int tid  = threadIdx.x;
    const int wv   = tid >> 6;
    const int lane = tid & 63;
    const int kq   = wv * 256;
    float* bufW = buf + wv * (64 * 65);

    // Load this WG's weight rows into LDS once (resident for all 512 steps).
    const float* Wa = isL1 ? Wih1 : Wih0;    // k-half 0 (input half)
    const float* Wb = isL1 ? Whh1 : Whh0;    // k-half 1 (recurrent half)
    for (int idx = tid; idx < ROWS * 256; idx += 256) {
        const int r  = idx >> 8;
        const int k4 = (idx & 255) * 4;
        *(float4*)(Wl + r * KK + k4)        = *(const float4*)(Wa + (size_t)(rbase + r) * HH + k4);
        *(float4*)(Wl + r * KK + 1024 + k4) = *(const float4*)(Wb + (size_t)(rbase + r) * HH + k4);
    }
    const int er = tid & 7;  // output row (same for tid and tid+256)
    const float bsum = isL1 ? (bih1[rbase + er] + bhh1[rbase + er])
                            : (bih0[rbase + er] + bhh0[rbase + er]);
    __syncthreads();

    for (int t = 0; t < TT; ++t) {
        float acc[ROWS];
        #pragma unroll
        for (int r = 0; r < ROWS; ++r) acc[r] = 0.f;

        if (!isL1) {
            // Phase A: x[t] half — no dependency, hides the wait below.
            // Normal cached loads: x is read-only, WGs on an XCD share it in L2.
            stage_and_accum<false>(x + (size_t)t * BH, Wl, bufW, kq, 0, lane, acc);
            if (tid == 0) {
                if (t >= 1)      spin_ge(c0 + (t - 1), NWGL);      // h0[t-1] ready
                if (t >= RING_D) spin_ge(c1 + (t - RING_D), NWGL); // ring slot reusable
            }
            __syncthreads();
            // Phase B: h0[t-1] half (recurrent, W_hh0 => wof 1024), sc1 reads
            const float* hp = (t == 0) ? h0init
                                       : ring + (size_t)((t - 1) % RING_D) * BH;
            stage_and_accum<true>(hp, Wl, bufW, kq, 1024, lane, acc);
        } else {
            if (tid == 0 && t >= 1) {
                spin_ge(c1 + (t - 1), NWGL);   // h1[t-1] ready
            }
            __syncthreads();
            // Phase A: h1[t-1] half (recurrent, W_hh1 => wof 1024), sc1 reads
            const float* hp = (t == 0) ? (h0init + BH)
                                       : (out + (size_t)(t - 1) * BH);
            stage_and_accum<true>(hp, Wl, bufW, kq, 1024, lane, acc);
            if (tid == 0) {
                spin_ge(c0 + t, NWGL);         // h0[t] ready
            }
            __syncthreads();
            // Phase B: h0[t] half (input half, W_ih1 => wof 0), sc1 reads
            stage_and_accum<true>(ring + (size_t)(t % RING_D) * BH, Wl, bufW, kq, 0, lane, acc);
        }

        // Cross-wave reduction: partials [w][b][r]
        float* pw = parts + (size_t)(wv * 64 + lane) * ROWS;
        *(float4*)(pw + 0) = make_float4(acc[0], acc[1], acc[2], acc[3]);
        *(float4*)(pw + 4) = make_float4(acc[4], acc[5], acc[6], acc[7]);
        __syncthreads();

        for (int o = tid; o < 512; o += 256) {
            const int b = o >> 3;
            const int r = o & 7;
            const float s = parts[o] + parts[o + 512] + parts[o + 1024] + parts[o + 1536] + bsum;
            const float hv = tanhf(s);
            const int col = rbase + r;
            if (!isL1) {
                st_agent(ring + (size_t)(t % RING_D) * BH + b * HH + col, hv);
                if (t == TT - 1) st_agent(out + (size_t)TT * BH + b * HH + col, hv);      // h0_n
            } else {
                st_agent(out + (size_t)t * BH + b * HH + col, hv);                        // outputs
                if (t == TT - 1) st_agent(out + (size_t)TT * BH + BH + b * HH + col, hv); // h1_n
            }
        }
        // __syncthreads drains vmcnt(0) per wave before s_barrier => after the
        // barrier ALL waves' sc1 write-throughs are at the coherence point.
        __syncthreads();
        if (tid == 0) {
            asm volatile("s_waitcnt vmcnt(0)" ::: "memory");  // belt-and-braces
            __hip_atomic_fetch_add(isL1 ? (c1 + t) : (c0 + t), 1,
                                   __ATOMIC_RELAXED, __HIP_MEMORY_SCOPE_AGENT);
        }
    }
}

extern "C" void kernel_launch(void* const* d_in, const int* in_sizes, int n_in,
                              void* d_out, int out_size, void* d_ws, size_t ws_size,
                              hipStream_t stream) {
    const float* x    = (const float*)d_in[0];
    const float* h0i  = (const float*)d_in[1];
    const float* Wih0 = (const float*)d_in[2];
    const float* bih0 = (const float*)d_in[3];
    const float* Whh0 = (const float*)d_in[4];
    const float* bhh0 = (const float*)d_in[5];
    const float* Wih1 = (const float*)d_in[6];
    const float* bih1 = (const float*)d_in[7];
    const float* Whh1 = (const float*)d_in[8];
    const float* bhh1 = (const float*)d_in[9];
    float* out = (float*)d_out;

    int*   c0   = (int*)d_ws;             // [512]
    int*   c1   = c0 + 512;               // [512]
    float* ring = (float*)((char*)d_ws + 8192);  // [RING_D][B][H]

    (void)hipFuncSetAttribute((const void*)rnn_persist,
                              hipFuncAttributeMaxDynamicSharedMemorySize,
                              LDS_FLOATS * 4);

    rnn_init<<<4, 256, 0, stream>>>(c0);
    rnn_persist<<<256, 256, LDS_FLOATS * 4, stream>>>(
        x, h0i, Wih0, bih0, Whh0, bhh0, Wih1, bih1, Whh1, bhh1,
        out, c0, c1, ring);
}